// Round 1
// baseline (142.355 us; speedup 1.0000x reference)
//
#include <hip/hip_runtime.h>
#include <cmath>

#define DIM 128
#define NHALF 4096
#define NROWS 8192
// FRAG_SCALE^2 = log2(e)/tau = 1.4426950408889634/0.5
#define FRAG_SCALE 1.69864368f
#define LN2 0.69314718056f

typedef __attribute__((ext_vector_type(8))) short bf16x8;
typedef __attribute__((ext_vector_type(4))) float f32x4;

static __device__ __forceinline__ unsigned short f32_to_bf16(float f) {
  unsigned int u = __float_as_uint(f);
  u = (u + 0x7FFFu + ((u >> 16) & 1u)) >> 16;
  return (unsigned short)u;
}
static __device__ __forceinline__ float bf16_to_f32(unsigned short h) {
  return __uint_as_float(((unsigned int)h) << 16);
}

// One wave per row: L2-normalize, scale by sqrt(log2e/tau), store bf16.
// Also zeroes rowsum[r] (used by atomics in the main kernel).
__global__ __launch_bounds__(256) void normalize_kernel(
    const float* __restrict__ z_i, const float* __restrict__ z_j,
    unsigned short* __restrict__ A, float* __restrict__ rowsum) {
  int wave = threadIdx.x >> 6;
  int lane = threadIdx.x & 63;
  int r = blockIdx.x * 4 + wave;
  const float* src = (r < NHALF) ? (z_i + (size_t)r * DIM)
                                 : (z_j + (size_t)(r - NHALF) * DIM);
  float2 v = *(const float2*)(src + 2 * lane);
  float ss = v.x * v.x + v.y * v.y;
#pragma unroll
  for (int off = 1; off < 64; off <<= 1) ss += __shfl_xor(ss, off);
  float norm = sqrtf(ss);
  float s = FRAG_SCALE / fmaxf(norm, 1e-8f);
  unsigned short b0 = f32_to_bf16(v.x * s);
  unsigned short b1 = f32_to_bf16(v.y * s);
  unsigned int packed = (unsigned int)b0 | ((unsigned int)b1 << 16);
  ((unsigned int*)A)[(size_t)r * (DIM / 2) + lane] = packed;
  if (lane == 0) rowsum[r] = 0.0f;
}

// One wave per row: pos[r] = sim[r, partner] = (scaled dot) * ln2
__global__ __launch_bounds__(256) void pos_kernel(
    const unsigned short* __restrict__ A, float* __restrict__ pos) {
  int wave = threadIdx.x >> 6;
  int lane = threadIdx.x & 63;
  int r = blockIdx.x * 4 + wave;
  int p = (r < NHALF) ? r + NHALF : r - NHALF;
  unsigned int ua = ((const unsigned int*)A)[(size_t)r * (DIM / 2) + lane];
  unsigned int ub = ((const unsigned int*)A)[(size_t)p * (DIM / 2) + lane];
  float a0 = bf16_to_f32((unsigned short)(ua & 0xFFFF));
  float a1 = bf16_to_f32((unsigned short)(ua >> 16));
  float b0 = bf16_to_f32((unsigned short)(ub & 0xFFFF));
  float b1 = bf16_to_f32((unsigned short)(ub >> 16));
  float d = a0 * b0 + a1 * b1;
#pragma unroll
  for (int off = 1; off < 64; off <<= 1) d += __shfl_xor(d, off);
  if (lane == 0) pos[r] = d * LN2;
}

// Main: per workgroup a 128x128 tile of exp2(pn_s . pn_s^T), diagonal masked,
// row-sums accumulated into rowsum[] via atomics.
// LDS: K split in two 64-wide halves, stride 72 (pad +8) -> 2-way conflicts only.
#define LDS_STRIDE 72
__global__ __launch_bounds__(256) void simexp_kernel(
    const unsigned short* __restrict__ A, float* __restrict__ rowsum) {
  __shared__ unsigned short Alds[128 * LDS_STRIDE];
  __shared__ unsigned short Blds[128 * LDS_STRIDE];
  const int tid = threadIdx.x;
  const int lane = tid & 63;
  const int w = tid >> 6;
  const int q = lane >> 4;
  const int n = lane & 15;
  const int rbBase = blockIdx.y * 128;
  const int cbBase = blockIdx.x * 128;
  const int wrow = (w & 1) * 64;
  const int wcol = (w >> 1) * 64;

  f32x4 acc[16];
#pragma unroll
  for (int i = 0; i < 16; i++)
#pragma unroll
    for (int j = 0; j < 4; j++) acc[i][j] = 0.0f;

  const unsigned short* Ag = A + (size_t)rbBase * DIM;
  const unsigned short* Bg = A + (size_t)cbBase * DIM;

#pragma unroll
  for (int h = 0; h < 2; ++h) {
    if (h) __syncthreads();
    // stage 128 rows x 64 cols per matrix: 1024 16B-chunks, 4 per thread
#pragma unroll
    for (int i = 0; i < 4; i++) {
      int c = tid + i * 256;
      int row = c >> 3;
      int cc = c & 7;
      int gcol = h * 64 + cc * 8;
      *(uint4*)&Alds[row * LDS_STRIDE + cc * 8] =
          *(const uint4*)(Ag + row * DIM + gcol);
      *(uint4*)&Blds[row * LDS_STRIDE + cc * 8] =
          *(const uint4*)(Bg + row * DIM + gcol);
    }
    __syncthreads();

    bf16x8 af[8];
#pragma unroll
    for (int mi = 0; mi < 4; mi++)
#pragma unroll
      for (int k2 = 0; k2 < 2; k2++)
        af[mi * 2 + k2] = *(const bf16x8*)&Alds[(wrow + mi * 16 + n) * LDS_STRIDE +
                                                k2 * 32 + q * 8];
#pragma unroll
    for (int ni = 0; ni < 4; ni++) {
      bf16x8 b0 = *(const bf16x8*)&Blds[(wcol + ni * 16 + n) * LDS_STRIDE + q * 8];
      bf16x8 b1 =
          *(const bf16x8*)&Blds[(wcol + ni * 16 + n) * LDS_STRIDE + 32 + q * 8];
#pragma unroll
      for (int mi = 0; mi < 4; mi++) {
        acc[mi * 4 + ni] = __builtin_amdgcn_mfma_f32_16x16x32_bf16(
            af[mi * 2], b0, acc[mi * 4 + ni], 0, 0, 0);
        acc[mi * 4 + ni] = __builtin_amdgcn_mfma_f32_16x16x32_bf16(
            af[mi * 2 + 1], b1, acc[mi * 4 + ni], 0, 0, 0);
      }
    }
  }

  // epilogue: exp2 + diagonal mask, accumulate per-(mi,reg) row slot
  float eacc[16];
#pragma unroll
  for (int i = 0; i < 16; i++) eacc[i] = 0.0f;
#pragma unroll
  for (int mi = 0; mi < 4; mi++) {
#pragma unroll
    for (int ni = 0; ni < 4; ni++) {
#pragma unroll
      for (int rg = 0; rg < 4; rg++) {
        float t = acc[mi * 4 + ni][rg];
        int grow = rbBase + wrow + mi * 16 + q * 4 + rg;
        int gcol = cbBase + wcol + ni * 16 + n;
        float e = exp2f(t);
        eacc[mi * 4 + rg] += (grow == gcol) ? 0.0f : e;
      }
    }
  }
  // reduce across the 16 lanes of each q-group, one atomic per row
#pragma unroll
  for (int mi = 0; mi < 4; mi++) {
#pragma unroll
    for (int rg = 0; rg < 4; rg++) {
      float v = eacc[mi * 4 + rg];
      v += __shfl_xor(v, 1);
      v += __shfl_xor(v, 2);
      v += __shfl_xor(v, 4);
      v += __shfl_xor(v, 8);
      if (n == 0) {
        atomicAdd(&rowsum[rbBase + wrow + mi * 16 + q * 4 + rg], v);
      }
    }
  }
}

// loss = mean over rows of log(rowsum) - pos
__global__ __launch_bounds__(256) void finalize_kernel(
    const float* __restrict__ rowsum, const float* __restrict__ pos,
    float* __restrict__ out) {
  int tid = threadIdx.x;
  float local = 0.0f;
  for (int r = tid; r < NROWS; r += 256) local += logf(rowsum[r]) - pos[r];
#pragma unroll
  for (int off = 1; off < 64; off <<= 1) local += __shfl_xor(local, off);
  __shared__ float wsum[4];
  if ((tid & 63) == 0) wsum[tid >> 6] = local;
  __syncthreads();
  if (tid == 0)
    out[0] = (wsum[0] + wsum[1] + wsum[2] + wsum[3]) * (1.0f / (float)NROWS);
}

extern "C" void kernel_launch(void* const* d_in, const int* in_sizes, int n_in,
                              void* d_out, int out_size, void* d_ws,
                              size_t ws_size, hipStream_t stream) {
  const float* z_i = (const float*)d_in[0];
  const float* z_j = (const float*)d_in[1];
  float* out = (float*)d_out;

  unsigned short* A = (unsigned short*)d_ws;                    // 8192*128 bf16 = 2 MB
  float* rowsum = (float*)((char*)d_ws + 2097152);              // 32 KB
  float* pos = (float*)((char*)d_ws + 2097152 + 32768);         // 32 KB

  normalize_kernel<<<NROWS / 4, 256, 0, stream>>>(z_i, z_j, A, rowsum);
  pos_kernel<<<NROWS / 4, 256, 0, stream>>>(A, pos);
  dim3 grid(64, 64);
  simexp_kernel<<<grid, 256, 0, stream>>>(A, rowsum);
  finalize_kernel<<<1, 256, 0, stream>>>(rowsum, pos, out);
}

// Round 2
// 123.852 us; speedup vs baseline: 1.1494x; 1.1494x over previous
//
#include <hip/hip_runtime.h>
#include <cmath>

#define DIM 128
#define NHALF 4096
#define NROWS 8192
// FRAG_SCALE^2 = log2(e)/tau = 1.4426950408889634/0.5
#define FRAG_SCALE 1.69864368f

typedef __attribute__((ext_vector_type(8))) short bf16x8;
typedef __attribute__((ext_vector_type(4))) float f32x4;

static __device__ __forceinline__ unsigned short f32_to_bf16(float f) {
  unsigned int u = __float_as_uint(f);
  u = (u + 0x7FFFu + ((u >> 16) & 1u)) >> 16;
  return (unsigned short)u;
}

// One wave per pair r in [0,4096): L2-normalize z_i[r], z_j[r], scale by
// sqrt(log2e/tau), store bf16 rows r and r+4096; pos[r]=pos[r+4096] =
// dot(zi,zj)/(|zi||zj|)/tau computed in fp32 (more accurate than bf16 path).
// Also zeroes rowsum.
__global__ __launch_bounds__(256) void prep_kernel(
    const float* __restrict__ z_i, const float* __restrict__ z_j,
    unsigned short* __restrict__ A, float* __restrict__ rowsum,
    float* __restrict__ pos) {
  int wave = threadIdx.x >> 6;
  int lane = threadIdx.x & 63;
  int r = blockIdx.x * 4 + wave;
  float2 a = *(const float2*)(z_i + (size_t)r * DIM + 2 * lane);
  float2 b = *(const float2*)(z_j + (size_t)r * DIM + 2 * lane);
  float sa = a.x * a.x + a.y * a.y;
  float sb = b.x * b.x + b.y * b.y;
  float dp = a.x * b.x + a.y * b.y;
#pragma unroll
  for (int off = 1; off < 64; off <<= 1) {
    sa += __shfl_xor(sa, off);
    sb += __shfl_xor(sb, off);
    dp += __shfl_xor(dp, off);
  }
  float na = fmaxf(sqrtf(sa), 1e-8f);
  float nb = fmaxf(sqrtf(sb), 1e-8f);
  float si = FRAG_SCALE / na;
  float sj = FRAG_SCALE / nb;
  unsigned int pa = (unsigned int)f32_to_bf16(a.x * si) |
                    ((unsigned int)f32_to_bf16(a.y * si) << 16);
  unsigned int pb = (unsigned int)f32_to_bf16(b.x * sj) |
                    ((unsigned int)f32_to_bf16(b.y * sj) << 16);
  ((unsigned int*)A)[(size_t)r * (DIM / 2) + lane] = pa;
  ((unsigned int*)A)[(size_t)(r + NHALF) * (DIM / 2) + lane] = pb;
  if (lane == 0) {
    float p = dp / (na * nb) * 2.0f;  // /tau, tau=0.5
    pos[r] = p;
    pos[r + NHALF] = p;
    rowsum[r] = 0.0f;
    rowsum[r + NHALF] = 0.0f;
  }
}

// Upper-triangle tiles only (sim is symmetric): 2080 workgroups, each a
// 128x128 tile. LDS-free: MFMA fragments loaded directly from global (A is
// 2 MB, L2-resident). Each exp2 credited to its row sum, and (off-diagonal
// tiles) also to its column's row sum.
__global__ __launch_bounds__(256) void simexp_kernel(
    const unsigned short* __restrict__ A, float* __restrict__ rowsum) {
  const int tid = threadIdx.x;
  const int lane = tid & 63;
  const int w = tid >> 6;
  const int q = lane >> 4;
  const int n = lane & 15;

  // decode upper-triangle tile index t -> (bi, bj), bi <= bj, 64 blocks
  int t = blockIdx.x;
  int bi = (int)((129.0f - sqrtf(16641.0f - 8.0f * (float)t)) * 0.5f);
  int start = 64 * bi - (bi * (bi - 1)) / 2;
  if (t < start) {
    bi--;
    start = 64 * bi - (bi * (bi - 1)) / 2;
  } else if (t >= start + (64 - bi)) {
    start += 64 - bi;
    bi++;
  }
  int bj = bi + (t - start);

  const int rbBase = bi * 128;
  const int cbBase = bj * 128;
  const int wrow = (w & 1) * 64;
  const int wcol = (w >> 1) * 64;
  const bool diag = (bi == bj);

  const unsigned short* Arow = A + (size_t)(rbBase + wrow) * DIM;
  const unsigned short* Brow = A + (size_t)(cbBase + wcol) * DIM;

  f32x4 acc[16];
#pragma unroll
  for (int i = 0; i < 16; i++)
#pragma unroll
    for (int j = 0; j < 4; j++) acc[i][j] = 0.0f;

#pragma unroll
  for (int kc = 0; kc < 4; kc++) {
    bf16x8 af[4], bfr[4];
#pragma unroll
    for (int mi = 0; mi < 4; mi++)
      af[mi] = *(const bf16x8*)(Arow + (mi * 16 + n) * DIM + kc * 32 + q * 8);
#pragma unroll
    for (int ni = 0; ni < 4; ni++)
      bfr[ni] = *(const bf16x8*)(Brow + (ni * 16 + n) * DIM + kc * 32 + q * 8);
#pragma unroll
    for (int mi = 0; mi < 4; mi++)
#pragma unroll
      for (int ni = 0; ni < 4; ni++)
        acc[mi * 4 + ni] = __builtin_amdgcn_mfma_f32_16x16x32_bf16(
            af[mi], bfr[ni], acc[mi * 4 + ni], 0, 0, 0);
  }

  // epilogue: exp2, diagonal mask, row + column accumulation
  float eaccR[16];
  float eaccC[4];
#pragma unroll
  for (int i = 0; i < 16; i++) eaccR[i] = 0.0f;
#pragma unroll
  for (int i = 0; i < 4; i++) eaccC[i] = 0.0f;
#pragma unroll
  for (int mi = 0; mi < 4; mi++) {
#pragma unroll
    for (int ni = 0; ni < 4; ni++) {
#pragma unroll
      for (int rg = 0; rg < 4; rg++) {
        float v = acc[mi * 4 + ni][rg];
        float e = __builtin_amdgcn_exp2f(v);
        int grow = rbBase + wrow + mi * 16 + q * 4 + rg;
        int gcol = cbBase + wcol + ni * 16 + n;
        e = (grow == gcol) ? 0.0f : e;
        eaccR[mi * 4 + rg] += e;
        eaccC[ni] += e;
      }
    }
  }
  // row sums: reduce across n (16 lanes per q-group), one atomic slot per row
#pragma unroll
  for (int mi = 0; mi < 4; mi++) {
#pragma unroll
    for (int rg = 0; rg < 4; rg++) {
      float v = eaccR[mi * 4 + rg];
      v += __shfl_xor(v, 1);
      v += __shfl_xor(v, 2);
      v += __shfl_xor(v, 4);
      v += __shfl_xor(v, 8);
      if (n == 0)
        atomicAdd(&rowsum[rbBase + wrow + mi * 16 + q * 4 + rg], v);
    }
  }
  // column sums (symmetry credit) for off-diagonal tiles
  if (!diag) {
#pragma unroll
    for (int ni = 0; ni < 4; ni++) {
      float v = eaccC[ni];
      v += __shfl_xor(v, 16);
      v += __shfl_xor(v, 32);
      if (lane < 16) atomicAdd(&rowsum[cbBase + wcol + ni * 16 + n], v);
    }
  }
}

// loss = mean over rows of log(rowsum) - pos  (log2-domain: rowsum holds
// sum of exp already in natural scale since exp2(x*log2e)=exp(x))
__global__ __launch_bounds__(256) void finalize_kernel(
    const float* __restrict__ rowsum, const float* __restrict__ pos,
    float* __restrict__ out) {
  int tid = threadIdx.x;
  float local = 0.0f;
  for (int r = tid; r < NROWS; r += 256) local += logf(rowsum[r]) - pos[r];
#pragma unroll
  for (int off = 1; off < 64; off <<= 1) local += __shfl_xor(local, off);
  __shared__ float wsum[4];
  if ((tid & 63) == 0) wsum[tid >> 6] = local;
  __syncthreads();
  if (tid == 0)
    out[0] = (wsum[0] + wsum[1] + wsum[2] + wsum[3]) * (1.0f / (float)NROWS);
}

extern "C" void kernel_launch(void* const* d_in, const int* in_sizes, int n_in,
                              void* d_out, int out_size, void* d_ws,
                              size_t ws_size, hipStream_t stream) {
  const float* z_i = (const float*)d_in[0];
  const float* z_j = (const float*)d_in[1];
  float* out = (float*)d_out;

  unsigned short* A = (unsigned short*)d_ws;            // 8192*128 bf16 = 2 MB
  float* rowsum = (float*)((char*)d_ws + 2097152);      // 32 KB
  float* pos = (float*)((char*)d_ws + 2097152 + 32768); // 32 KB

  prep_kernel<<<NHALF / 4, 256, 0, stream>>>(z_i, z_j, A, rowsum, pos);
  simexp_kernel<<<2080, 256, 0, stream>>>(A, rowsum);
  finalize_kernel<<<1, 256, 0, stream>>>(rowsum, pos, out);
}